// Round 6
// baseline (196.745 us; speedup 1.0000x reference)
//
#include <hip/hip_runtime.h>
#include <hip/hip_bf16.h>

#define BB   8
#define TT   1024
#define NCBN 2
#define DD   128
#define KK   8192
#define MM   8192          // B*T queries per codebook

constexpr int OUT_IDX_OFF  = BB * 256 * TT;                // 2097152
constexpr int OUT_LOSS_OFF = OUT_IDX_OFF + BB * NCBN * TT; // 2113536

#define THR   0.45f        // >= 2*worst-case |y_bf16 - y_f32| (bound ~0.34)
#define QCAP  512
#define NSPL  8            // K-splits (1024 codes each)

typedef __attribute__((ext_vector_type(8))) short   short8;   // 8 bf16
typedef __attribute__((ext_vector_type(4))) float   float4v;

__device__ __forceinline__ unsigned short f2bf(float v) {
    unsigned u = __float_as_uint(v);
    return (unsigned short)((u + 0x7FFFu + ((u >> 16) & 1u)) >> 16);  // RNE
}

__device__ __forceinline__ void gl_lds16(const void* g, void* l) {
    __builtin_amdgcn_global_load_lds(
        (const __attribute__((address_space(1))) unsigned int*)g,
        (__attribute__((address_space(3))) unsigned int*)l, 16, 0, 0);
}

__device__ __forceinline__ unsigned fmono(float v) {   // order-preserving u32
    unsigned u = __float_as_uint(v);
    return (u & 0x80000000u) ? ~u : (u | 0x80000000u);
}
__device__ __forceinline__ float fmono_inv(unsigned mu) {
    unsigned u = (mu & 0x80000000u) ? (mu & 0x7FFFFFFFu) : ~mu;
    return __uint_as_float(u);
}

// ---------------------------------------------------------------------------
// Prep kernel. Blocks 0..255: pack_x tile (transpose + bf16 + x2 + x32t +
// pmin/gmin init). Blocks 256..319: pack_c (64 rows each, bf16 + c2).
// All reductions use the R1 ascending-d fmaf association (bit-exact).
// ---------------------------------------------------------------------------
__global__ __launch_bounds__(256)
void prep_kernel(const float* __restrict__ x, const float* __restrict__ cb,
                 unsigned short* __restrict__ xbf, unsigned short* __restrict__ cbf,
                 float* __restrict__ x2, float* __restrict__ c2,
                 float* __restrict__ x32t, int contig,
                 unsigned long long* __restrict__ pmin,
                 unsigned int* __restrict__ gminU,
                 float* __restrict__ out) {
    const int bx = blockIdx.x;
    const int tid = threadIdx.x;

    if (bx >= 256) {   // ---- pack_c
        int g = (bx - 256) * 256 + tid;   // n*K + k
        if (g == 0) out[OUT_LOSS_OFF] = 0.f;
        const float4* crow = (const float4*)(cb + (size_t)g * DD);
        unsigned short* orow = cbf + (size_t)g * DD;
        float s = 0.f;
#pragma unroll 4
        for (int i2 = 0; i2 < 16; ++i2) {
            float4 v0 = crow[2 * i2];
            float4 v1 = crow[2 * i2 + 1];
            s = fmaf(v0.x, v0.x, s); s = fmaf(v0.y, v0.y, s);
            s = fmaf(v0.z, v0.z, s); s = fmaf(v0.w, v0.w, s);
            s = fmaf(v1.x, v1.x, s); s = fmaf(v1.y, v1.y, s);
            s = fmaf(v1.z, v1.z, s); s = fmaf(v1.w, v1.w, s);
            uint4 pk;
            pk.x = (unsigned)f2bf(v0.x) | ((unsigned)f2bf(v0.y) << 16);
            pk.y = (unsigned)f2bf(v0.z) | ((unsigned)f2bf(v0.w) << 16);
            pk.z = (unsigned)f2bf(v1.x) | ((unsigned)f2bf(v1.y) << 16);
            pk.w = (unsigned)f2bf(v1.z) | ((unsigned)f2bf(v1.w) << 16);
            *(uint4*)(orow + i2 * 8) = pk;
        }
        c2[g] = s;
        return;
    }

    // ---- pack_x: bx = ((b<<1)|n)*16 + t-tile
    __shared__ float Ld[DD][65];
    const int b = bx >> 5, n = (bx >> 4) & 1;
    const int t0 = (bx & 15) * 64;

    const float* base = x + ((size_t)(b * 256 + n * 128)) * TT + t0;
    const int dro = tid >> 2, q4 = tid & 3;
#pragma unroll
    for (int half = 0; half < 2; ++half) {
        int d = dro + half * 64;
        const float* rp = base + (size_t)d * TT + q4 * 16;
#pragma unroll
        for (int j = 0; j < 4; ++j) {
            float4 v = *(const float4*)(rp + j * 4);
            int t = q4 * 16 + j * 4;
            Ld[d][t + 0] = v.x; Ld[d][t + 1] = v.y;
            Ld[d][t + 2] = v.z; Ld[d][t + 3] = v.w;
        }
    }
    __syncthreads();

    if (tid < 64) {
        float s = 0.f;
        for (int d = 0; d < DD; ++d) { float v = Ld[d][tid]; s = fmaf(v, v, s); }
        size_t gi = (size_t)n * MM + b * TT + t0 + tid;
        x2[gi] = s;
        pmin[gi] = 0xFFFFFFFFFFFFFFFFull;
        gminU[gi] = 0xFFFFFFFFu;
    }

    unsigned short* orow0 = xbf + ((size_t)n * MM + b * TT + t0) * DD;
#pragma unroll
    for (int pp = 0; pp < 4; ++pp) {
        int u = tid + pp * 256;            // 1024 units = 64 rows x 16 segs
        int tt = u >> 4, sg = u & 15;
        unsigned short tmp[8];
#pragma unroll
        for (int j = 0; j < 8; ++j) tmp[j] = f2bf(Ld[sg * 8 + j][tt]);
        uint4 pk;
        pk.x = (unsigned)tmp[0] | ((unsigned)tmp[1] << 16);
        pk.y = (unsigned)tmp[2] | ((unsigned)tmp[3] << 16);
        pk.z = (unsigned)tmp[4] | ((unsigned)tmp[5] << 16);
        pk.w = (unsigned)tmp[6] | ((unsigned)tmp[7] << 16);
        *(uint4*)(orow0 + (size_t)tt * DD + sg * 8) = pk;
    }

    if (contig) {   // fp32 transposed copy for fast exact rescore
        float* xrow0 = x32t + ((size_t)n * MM + b * TT + t0) * DD;
#pragma unroll
        for (int pp = 0; pp < 8; ++pp) {
            int u = tid + pp * 256;        // 2048 units = 64 rows x 32 f4-segs
            int tt = u >> 5, sg = u & 31;
            float4 v = { Ld[sg * 4 + 0][tt], Ld[sg * 4 + 1][tt],
                         Ld[sg * 4 + 2][tt], Ld[sg * 4 + 3][tt] };
            *(float4*)(xrow0 + (size_t)tt * DD + sg * 4) = v;
        }
    }
}

// ---------------------------------------------------------------------------
// Exact fp32 rescore: bit-identical association to the R1 passing kernel
// (ascending-d fmaf; s = (x2 - 2*xc) + c2). atomicMin on (s_bits<<32 | k)
// = "min s, then lowest k" (s > 0 here) = np first-occurrence argmin.
// ---------------------------------------------------------------------------
__device__ void rescore_one(int n, int m, int k,
                            const float* __restrict__ xex, int contig,
                            const float* __restrict__ cb,
                            const float* __restrict__ x2, const float* __restrict__ c2,
                            unsigned long long* __restrict__ pmin) {
    const float* xp; int st;
    if (contig) { xp = xex + ((size_t)n * MM + m) * DD; st = 1; }
    else {
        int b = m >> 10, t = m & (TT - 1);
        xp = xex + ((size_t)(b * 256 + n * 128)) * TT + t; st = TT;
    }
    const float* cp = cb + ((size_t)(n * KK + k)) * DD;
    float xc = 0.f;
    for (int d = 0; d < DD; ++d)
        xc = fmaf(xp[(size_t)d * st], cp[d], xc);
    float u = x2[(size_t)n * MM + m] - 2.0f * xc;
    float s = u + c2[n * KK + k];
    unsigned long long pk = ((unsigned long long)__float_as_uint(s) << 32) | (unsigned)k;
    atomicMin(pmin + (size_t)n * MM + m, pk);
}

// ---------------------------------------------------------------------------
// Screening v6. grid 1024 x 256 thr (4 blocks/CU). id&15 -> (n, ks of 8);
// qt = id>>4. Block tile 128 q x 1024 codes, chunks of 128 (8/phase).
// Single 32 KB LDS buffer: queries staged -> bfr regs -> reused for codes.
// Phase 0: bf16 min per query; merged to LDS minU AND global gminU.
// Phase 1: rescan, collect (y, q, code) with y <= local_min+THR into queue.
// Drain: filter vs global gmin+THR (provably retains exact argmin), rescore.
// ---------------------------------------------------------------------------
__global__ __launch_bounds__(256, 2)
void screen_kernel(const unsigned short* __restrict__ xbf,
                   const unsigned short* __restrict__ cbf,
                   const float* __restrict__ c2,
                   const float* __restrict__ xex, int contig,
                   const float* __restrict__ cb32,
                   const float* __restrict__ x2,
                   unsigned int* __restrict__ gminU,
                   unsigned long long* __restrict__ pmin) {
    __shared__ __align__(16) unsigned short Bsh[128 * 128];   // 32 KB
    __shared__ unsigned int       minU[128];
    __shared__ float              c2s[128];
    __shared__ unsigned int       qcnt;
    __shared__ unsigned long long queue[QCAP];                // 4 KB

    const int tid = threadIdx.x;
    const int id  = blockIdx.x;
    const int n   = id & 1;
    const int ks  = (id >> 1) & 7;
    const int qt  = id >> 4;           // 0..63
    const int m0  = qt * 128;
    const int k0  = ks * 1024;

    const int wave = tid >> 6, lane = tid & 63;
    const int cw = wave & 1, qw = wave >> 1;
    const int quad = lane >> 4, l15 = lane & 15;

    // per-lane staging offsets (bytes within one 32 KB tile), 8 issues/wave
    int goff[8];
#pragma unroll
    for (int p = 0; p < 8; ++p) {
        int u   = (p * 4 + wave) * 64 + lane;
        int row = u >> 4;
        int seg = (u & 15) ^ (row & 15);
        goff[p] = (row * DD + seg * 8) * 2;
    }

    // ---- stage queries into Bsh (async)
    {
        const char* src = (const char*)(xbf + ((size_t)n * MM + m0) * DD);
#pragma unroll
        for (int p = 0; p < 8; ++p)
            gl_lds16(src + goff[p], &Bsh[(p * 4 + wave) * 512]);
    }
    if (tid < 128) minU[tid] = 0xFFFFFFFFu;
    if (tid == 0)  qcnt = 0;
    __syncthreads();

    // ---- query B-fragments (whole D=128) register-resident: 64 VGPRs
    short8 bfr[4][4];                      // [tq][k4]
#pragma unroll
    for (int tq = 0; tq < 4; ++tq) {
        int q = qw * 64 + tq * 16 + l15;   // q&15 == l15
#pragma unroll
        for (int k4 = 0; k4 < 4; ++k4) {
            int seg = k4 * 4 + quad;
            bfr[tq][k4] = *(const short8*)(&Bsh[q * 128 + ((seg ^ l15) * 8)]);
        }
    }

    float mloc[4] = {3.4e38f, 3.4e38f, 3.4e38f, 3.4e38f};
    float thr[4]  = {3.4e38f, 3.4e38f, 3.4e38f, 3.4e38f};

    const char*  asrc0 = (const char*)(cbf + ((size_t)n * KK + k0) * DD);
    const float* c2p   = c2 + (size_t)n * KK + k0;

#pragma unroll
    for (int phase = 0; phase < 2; ++phase) {
        for (int ch = 0; ch < 8; ++ch) {
            __syncthreads();               // Bsh free (bfr/prev chunk done)
            {   // async stage code chunk -> Bsh
                const char* src = asrc0 + (size_t)ch * (128 * DD * 2);
#pragma unroll
                for (int p = 0; p < 8; ++p)
                    gl_lds16(src + goff[p], &Bsh[(p * 4 + wave) * 512]);
                if (tid < 32)
                    *(float4*)&c2s[tid * 4] =
                        *(const float4*)(c2p + ch * 128 + tid * 4);
            }
            __syncthreads();               // Bsh ready

            float4v acc[4][4];             // [tc][tq]: 64 VGPRs
#pragma unroll
            for (int tc = 0; tc < 4; ++tc)
#pragma unroll
                for (int tq = 0; tq < 4; ++tq)
                    acc[tc][tq] = (float4v){0.f, 0.f, 0.f, 0.f};

#pragma unroll
            for (int k4 = 0; k4 < 4; ++k4) {
                short8 a[4];
#pragma unroll
                for (int tc = 0; tc < 4; ++tc) {
                    int r = cw * 64 + tc * 16 + l15;       // r&15 == l15
                    int seg = k4 * 4 + quad;
                    a[tc] = *(const short8*)(&Bsh[r * 128 + ((seg ^ l15) * 8)]);
                }
#pragma unroll
                for (int tc = 0; tc < 4; ++tc)
#pragma unroll
                    for (int tq = 0; tq < 4; ++tq)
                        acc[tc][tq] = __builtin_amdgcn_mfma_f32_16x16x32_bf16(
                            a[tc], bfr[tq][k4], acc[tc][tq], 0, 0, 0);
            }

            // epilogue: y = c2 - 2*xc  (x2 query-constant, argmin-invariant)
#pragma unroll
            for (int tc = 0; tc < 4; ++tc) {
                float4v c2r = *(const float4v*)(&c2s[cw * 64 + tc * 16 + quad * 4]);
#pragma unroll
                for (int tq = 0; tq < 4; ++tq) {
                    float y0 = fmaf(-2.0f, acc[tc][tq][0], c2r[0]);
                    float y1 = fmaf(-2.0f, acc[tc][tq][1], c2r[1]);
                    float y2 = fmaf(-2.0f, acc[tc][tq][2], c2r[2]);
                    float y3 = fmaf(-2.0f, acc[tc][tq][3], c2r[3]);
                    float m4 = fminf(fminf(y0, y1), fminf(y2, y3));
                    if (phase == 0) {
                        mloc[tq] = fminf(mloc[tq], m4);
                    } else if (m4 <= thr[tq]) {
                        float yv[4] = {y0, y1, y2, y3};
#pragma unroll
                        for (int rg = 0; rg < 4; ++rg) {
                            if (yv[rg] <= thr[tq]) {
                                unsigned idx  = atomicAdd(&qcnt, 1u);
                                unsigned code = (unsigned)(ch * 128 + cw * 64 + tc * 16 + quad * 4 + rg);
                                unsigned q    = (unsigned)(qw * 64 + tq * 16 + l15);
                                if (idx < QCAP)
                                    queue[idx] = ((unsigned long long)__float_as_uint(yv[rg]) << 32)
                                               | (q << 10) | code;
                                else rescore_one(n, m0 + (int)q, k0 + (int)code,
                                                 xex, contig, cb32, x2, c2, pmin);
                            }
                        }
                    }
                }
            }
        }

        if (phase == 0) {
            // merge per-query mins: shuffle across quads, then LDS atomicMin
#pragma unroll
            for (int tq = 0; tq < 4; ++tq) {
                float v = mloc[tq];
                v = fminf(v, __shfl_xor(v, 16, 64));
                v = fminf(v, __shfl_xor(v, 32, 64));
                if (quad == 0)
                    atomicMin(&minU[qw * 64 + tq * 16 + l15], fmono(v));
            }
            __syncthreads();
            if (tid < 128)   // publish to global running min (device scope)
                atomicMin(&gminU[(size_t)n * MM + m0 + tid], minU[tid]);
#pragma unroll
            for (int tq = 0; tq < 4; ++tq)
                thr[tq] = fmono_inv(minU[qw * 64 + tq * 16 + l15]) + THR;
        }
    }

    __syncthreads();
    // fetch freshest global mins -> LDS thresholds (atomic no-op read)
    if (tid < 128) {
        unsigned mu = atomicMin(&gminU[(size_t)n * MM + m0 + tid], 0xFFFFFFFFu);
        c2s[tid] = fmono_inv(mu) + THR;    // c2s reused as gthr
    }
    __syncthreads();

    unsigned total = qcnt; if (total > QCAP) total = QCAP;
    for (unsigned i = tid; i < total; i += 256) {
        unsigned long long e = queue[i];
        float y = __uint_as_float((unsigned)(e >> 32));
        unsigned q = ((unsigned)e >> 10) & 127u;
        unsigned code = (unsigned)e & 1023u;
        if (y <= c2s[q])
            rescore_one(n, m0 + (int)q, k0 + (int)code,
                        xex, contig, cb32, x2, c2, pmin);
    }
}

// ---------------------------------------------------------------------------
// Gather (transposed): stage selected code rows in LDS, write d-major
// coalesced, read x at same offsets for the loss.
// ---------------------------------------------------------------------------
__global__ __launch_bounds__(256)
void gather_kernel(const float* __restrict__ x, const float* __restrict__ cb,
                   const unsigned long long* __restrict__ pmin,
                   float* __restrict__ out) {
    __shared__ float Cr[64][DD + 1];   // 33 KB
    __shared__ int   kid[64];
    const int b = blockIdx.x >> 1, n = blockIdx.x & 1;
    const int t0 = blockIdx.y * 64;
    const int tid = threadIdx.x;

    if (tid < 64) {
        int t = t0 + tid;
        int k = (int)(pmin[(size_t)n * MM + b * TT + t] & 0xFFFFFFFFull);
        kid[tid] = k;
        out[OUT_IDX_OFF + (b * NCBN + n) * TT + t] = (float)k;
    }
    __syncthreads();

    {   // stage code rows: 4 lanes per row, coalesced 512 B per row
        int row = tid >> 2, q4 = tid & 3;
        const float* cp = cb + ((size_t)n * KK + kid[row]) * DD + q4 * 32;
#pragma unroll
        for (int j = 0; j < 8; ++j) {
            float4 v = *(const float4*)(cp + j * 4);
            int d = q4 * 32 + j * 4;
            Cr[row][d + 0] = v.x; Cr[row][d + 1] = v.y;
            Cr[row][d + 2] = v.z; Cr[row][d + 3] = v.w;
        }
    }
    __syncthreads();

    float lsum = 0.f;
    const float* xb = x  + ((size_t)(b * 256 + n * 128)) * TT + t0;
    float*       ob = out + ((size_t)(b * 256 + n * 128)) * TT + t0;
#pragma unroll
    for (int pp = 0; pp < 8; ++pp) {
        int u  = tid + pp * 256;       // 2048 units = 128 d x 16 float4
        int d  = u >> 4, ts = (u & 15) * 4;
        float4 xv = *(const float4*)(xb + (size_t)d * TT + ts);
        float4 qv = { Cr[ts + 0][d], Cr[ts + 1][d], Cr[ts + 2][d], Cr[ts + 3][d] };
        *(float4*)(ob + (size_t)d * TT + ts) = qv;
        float e;
        e = xv.x - qv.x; lsum = fmaf(e, e, lsum);
        e = xv.y - qv.y; lsum = fmaf(e, e, lsum);
        e = xv.z - qv.z; lsum = fmaf(e, e, lsum);
        e = xv.w - qv.w; lsum = fmaf(e, e, lsum);
    }

#pragma unroll
    for (int o = 32; o > 0; o >>= 1) lsum += __shfl_down(lsum, o, 64);
    __shared__ float wsum[4];
    int lane = tid & 63, w = tid >> 6;
    if (lane == 0) wsum[w] = lsum;
    __syncthreads();
    if (tid == 0) {
        float tot = wsum[0] + wsum[1] + wsum[2] + wsum[3];
        atomicAdd(out + OUT_LOSS_OFF, tot * 2.384185791015625e-7f);  // 2^-22
    }
}

// ---------------------------------------------------------------------------
extern "C" void kernel_launch(void* const* d_in, const int* in_sizes, int n_in,
                              void* d_out, int out_size, void* d_ws, size_t ws_size,
                              hipStream_t stream) {
    (void)in_sizes; (void)n_in; (void)out_size;
    const float* x  = (const float*)d_in[0];
    const float* cb = (const float*)d_in[1];
    float* out = (float*)d_out;

    char* ws = (char*)d_ws;
    unsigned short* xbf = (unsigned short*)(ws);                       // 4 MiB
    unsigned short* cbf = (unsigned short*)(ws + (4u << 20));          // 4 MiB
    float* x2 = (float*)(ws + (8u << 20));                             // 64 KiB
    float* c2 = (float*)(ws + (8u << 20) + (64u << 10));               // 64 KiB
    unsigned long long* pmin =
        (unsigned long long*)(ws + (8u << 20) + (128u << 10));         // 128 KiB
    unsigned int* gminU =
        (unsigned int*)(ws + (8u << 20) + (256u << 10));               // 64 KiB
    float* x32t = (float*)(ws + (9u << 20));                           // 16 MiB

    const size_t need = (9u << 20) + (size_t)NCBN * MM * DD * 4;
    const int contig = (ws_size >= need) ? 1 : 0;
    const float* xex = contig ? x32t : x;

    prep_kernel<<<dim3(320), 256, 0, stream>>>(x, cb, xbf, cbf, x2, c2,
                                               x32t, contig, pmin, gminU, out);
    screen_kernel<<<dim3(1024), 256, 0, stream>>>(xbf, cbf, c2, xex, contig,
                                                  cb, x2, gminU, pmin);
    gather_kernel<<<dim3(16, 16), 256, 0, stream>>>(x, cb, pmin, out);
}